// Round 5
// baseline (145.472 us; speedup 1.0000x reference)
//
#include <hip/hip_runtime.h>
#include <hip/hip_bf16.h>

// Nav_64939905516231 (VIN value iteration), MI355X gfx950.
// B=64,H=W=64,dim_h=150,n_hat=8,n_act=4,K=10. fp32 in/out, maze int32.
// Collapses: r = conv5x5(m,W_eff)+b_eff (150ch folded); q_t = q0 + conv5x5(v,w).
// R27: kill the spill at 4 waves/SIMD. R25/R26 showed launch_bounds(1024,4)
// caps arch VGPRs at 64 and does NOT spill to AGPR (15-25MB scratch traffic,
// VGPR_Count=64). Live set must be ~64: go to 1 channel/lane.
// Lane = (ch = lane>>3, p8 = (lane&7)*8). Weights 50->25 regs. Live ~63
// (25 w + 8 acc + 8 q0 + 12 taps + misc). Per-lane work unchanged (8 px-ch,
// 100 pk-FMA/sweep). Taps 8-way broadcast across ch groups; 8-ch max via
// shfl_xor(8,16,32); ch==0 lanes write combined row. q0g planar [b][r][ch][px]
// (lane q0 = 2 contiguous float4, coalesced). 16 waves, 1 blk/CU, 4 w/SIMD.
// 1 barrier/step, dbuf vbuf. ~44us ws fill + ~18us dispatch harness-fixed.

#define NHAT 8
#define DIMH 150

typedef float v2f __attribute__((ext_vector_type(2)));

// ------- rq: prep (parallel) + r = table-conv(maze) + q0 -------
// q0 layout: q0g[(((b*64+gy)*8 + ch)*64 + gx)] planar per channel.
__global__ __launch_bounds__(512) void rq_kernel(
    const int* __restrict__ maze, const float* __restrict__ emb,
    const float* __restrict__ encode_w, const float* __restrict__ encode_b,
    const float* __restrict__ r_w, const float* __restrict__ q_w,
    float* __restrict__ q0g) {
  __shared__ float wpart[5][50];
  __shared__ float bpart[152];
  __shared__ float weff[2][25];
  __shared__ float Ts[4][25];
  __shared__ float bsh;
  __shared__ v2f qw2[25][4];
  __shared__ unsigned char mzt[24][68];
  __shared__ float rt[20][68];

  int tid = threadIdx.x;
  int b = blockIdx.y, A0 = blockIdx.x * 16;

  // P0: weight stage + W_eff partials + maze tile
  if (tid < 100) {
    int k = tid >> 2, j = tid & 3;
    qw2[k][j] = (v2f){q_w[(2 * j) * 25 + k], q_w[(2 * j + 1) * 25 + k]};
  }
  if (tid >= 256 && tid < 506) {
    int t2 = tid - 256;
    int chunk = t2 / 50, ik = t2 % 50;
    int i = ik / 25, k = ik % 25;
    int c0 = chunk * 30;
    float s = 0.f;
    for (int c = c0; c < c0 + 30; ++c)
      s += r_w[c] * encode_w[c * 50 + i * 25 + k];
    wpart[chunk][ik] = s;
  }
  if (tid >= 100 && tid < 250) {
    int c = tid - 100;
    bpart[c] = r_w[c] * encode_b[c];
  }
  for (int i = tid; i < 24 * 68; i += 512) {
    int mr = i / 68, mc = i % 68;
    int gy = A0 - 4 + mr, gx = mc - 2;
    unsigned char v = 3;
    if (gy >= 0 && gy < 64 && gx >= 0 && gx < 64)
      v = (unsigned char)maze[(b * 64 + gy) * 64 + gx];
    mzt[mr][mc] = v;
  }
  __syncthreads();
  // P1: reduce
  if (tid < 50) {
    float s = 0.f;
#pragma unroll
    for (int ch = 0; ch < 5; ++ch) s += wpart[ch][tid];
    weff[tid / 25][tid % 25] = s;
  }
  if (tid == 50) {
    float s = 0.f;
    for (int c = 0; c < 150; ++c) s += bpart[c];
    bsh = s;
  }
  __syncthreads();
  // P2: T table
  if (tid < 100) {
    int val = tid / 25, k = tid % 25;
    float t = 0.f;
    if (val < 3) t = weff[0][k] * emb[val * 2] + weff[1][k] * emb[val * 2 + 1];
    Ts[val][k] = t;  // row 3 == 0 (padding sentinel)
  }
  __syncthreads();
  // P3: r tile rows [A0-2, A0+18)
  for (int i = tid; i < 20 * 68; i += 512) {
    int rr = i / 68, cc = i % 68;
    int gy = A0 - 2 + rr, gx = cc - 2;
    float v = 0.f;
    if (gy >= 0 && gy < 64 && gx >= 0 && gx < 64) {
      v = bsh;
#pragma unroll
      for (int ky = 0; ky < 5; ++ky)
#pragma unroll
        for (int kx = 0; kx < 5; ++kx)
          v += Ts[mzt[rr + ky][cc - 2 + kx]][ky * 5 + kx];
    }
    rt[rr][cc] = v;
  }
  __syncthreads();
  // P4: q0 on owned 16 rows -> planar [b][gy][ch][gx]
  for (int i = tid; i < 16 * 64; i += 512) {
    int ly = i >> 6, gx = i & 63;
    int gy = A0 + ly;
    v2f acc[4];
#pragma unroll
    for (int j = 0; j < 4; ++j) acc[j] = (v2f){0.f, 0.f};
#pragma unroll
    for (int ky = 0; ky < 5; ++ky)
#pragma unroll
      for (int kx = 0; kx < 5; ++kx) {
        int k = ky * 5 + kx;
        float vv = rt[ly + ky][gx + kx];
        v2f vv2 = (v2f){vv, vv};
#pragma unroll
        for (int j = 0; j < 4; ++j) acc[j] += qw2[k][j] * vv2;
      }
    size_t base = ((size_t)(b * 64 + gy) * 8) * 64 + gx;
#pragma unroll
    for (int j = 0; j < 4; ++j) {
      q0g[base + (size_t)(2 * j) * 64] = acc[j].x;
      q0g[base + (size_t)(2 * j + 1) * 64] = acc[j].y;
    }
  }
}

// =============== vi: 10 fused VI steps + projection =================
// Block (1024 thr = 16 waves) owns rows [a0, a0+16); grid 256 (1 blk/CU).
// Lane: ch = lane>>3 (channel 0..7), p8 = (lane&7)*8 (8-px group).
// Wave = 1 row x 64 px x 8 ch, r = s + wave (+16 stride), wave-uniform.
// All 8 ch groups read the SAME vbuf taps (broadcast). 8-ch max via
// shfl_xor(8,16,32); ch==0 writes cols 2+p8..9+p8. 1 barrier/step.
__global__ __launch_bounds__(1024, 4) void vi_kernel(
    const float* __restrict__ q0g, const float* __restrict__ w,
    const float* __restrict__ fc_w, float* __restrict__ out) {
  __shared__ __align__(16) float vbuf[2][60][68];  // 32.6 KB
  __shared__ float wl[25][8];

  int tid = threadIdx.x;
  int b = blockIdx.y, a0 = blockIdx.x * 16;
  int wave = tid >> 6, lane = tid & 63;
  int ch = lane >> 3;        // channel 0..7
  int p8 = (lane & 7) * 8;   // px group start

  if (tid < 200) {
    int k = tid >> 3, c = tid & 7;
    wl[k][c] = w[c * 25 + k];
  }
  for (int i = tid; i < 2 * 60 * 68; i += 1024) ((float*)vbuf)[i] = 0.f;
  __syncthreads();

  // this lane's 1 channel -> 25 scalar regs
  float wr[25];
#pragma unroll
  for (int k = 0; k < 25; ++k) wr[k] = wl[k][ch];

  const float* q0b = q0g + (size_t)b * 64 * 8 * 64;
  int cur = 0;

  // v0 = max_c q0 on [a0-20, a0+36): 8 strided planar loads per px
  {
    int s = max(0, a0 - 20), e = min(64, a0 + 36);
    int gx = lane;
    for (int r = s + wave; r < e; r += 16) {
      const float* qr = &q0b[((size_t)r * 8) * 64 + gx];
      float m = qr[0];
#pragma unroll
      for (int c = 1; c < 8; ++c) m = fmaxf(m, qr[(size_t)c * 64]);
      vbuf[0][r - a0 + 22][gx + 2] = m;
    }
  }
  __syncthreads();

  for (int t = 1; t <= 9; ++t) {
    int hh = 2 * (10 - t);
    int s = max(0, a0 - hh), e = min(64, a0 + 16 + hh);
    for (int r = s + wave; r < e; r += 16) {  // wave-uniform row
      int lr = r - a0 + 22;
      const float* qrow = &q0b[((size_t)r * 8 + ch) * 64 + p8];
      float4 qa = *(const float4*)qrow;
      float4 qb = *(const float4*)(qrow + 4);
      v2f acc[4];  // px pairs (p8+2j, p8+2j+1)
#pragma unroll
      for (int j = 0; j < 4; ++j) acc[j] = (v2f){0.f, 0.f};
#pragma unroll
      for (int jj = 0; jj < 5; ++jj) {
        const float* row = &vbuf[cur][lr - 2 + jj][p8];
        float4 fa = *(const float4*)row;
        float4 fb = *(const float4*)(row + 4);
        float4 fc = *(const float4*)(row + 8);
        float f[12] = {fa.x, fa.y, fa.z, fa.w, fb.x, fb.y,
                       fb.z, fb.w, fc.x, fc.y, fc.z, fc.w};
#pragma unroll
        for (int kx = 0; kx < 5; ++kx) {
          float wk = wr[jj * 5 + kx];
          v2f wk2 = (v2f){wk, wk};
#pragma unroll
          for (int j = 0; j < 4; ++j)
            acc[j] += wk2 * (v2f){f[2 * j + kx], f[2 * j + 1 + kx]};
        }
      }
      // q0 added after the tap chain: L2 latency hides under FMAs
      acc[0] += (v2f){qa.x, qa.y};
      acc[1] += (v2f){qa.z, qa.w};
      acc[2] += (v2f){qb.x, qb.y};
      acc[3] += (v2f){qb.z, qb.w};
      // max over 8 channels: butterfly over lane strides 8,16,32
      float m0 = acc[0].x, m1 = acc[0].y, m2 = acc[1].x, m3 = acc[1].y;
      float m4 = acc[2].x, m5 = acc[2].y, m6 = acc[3].x, m7 = acc[3].y;
      m0 = fmaxf(m0, __shfl_xor(m0, 8));  m0 = fmaxf(m0, __shfl_xor(m0, 16));  m0 = fmaxf(m0, __shfl_xor(m0, 32));
      m1 = fmaxf(m1, __shfl_xor(m1, 8));  m1 = fmaxf(m1, __shfl_xor(m1, 16));  m1 = fmaxf(m1, __shfl_xor(m1, 32));
      m2 = fmaxf(m2, __shfl_xor(m2, 8));  m2 = fmaxf(m2, __shfl_xor(m2, 16));  m2 = fmaxf(m2, __shfl_xor(m2, 32));
      m3 = fmaxf(m3, __shfl_xor(m3, 8));  m3 = fmaxf(m3, __shfl_xor(m3, 16));  m3 = fmaxf(m3, __shfl_xor(m3, 32));
      m4 = fmaxf(m4, __shfl_xor(m4, 8));  m4 = fmaxf(m4, __shfl_xor(m4, 16));  m4 = fmaxf(m4, __shfl_xor(m4, 32));
      m5 = fmaxf(m5, __shfl_xor(m5, 8));  m5 = fmaxf(m5, __shfl_xor(m5, 16));  m5 = fmaxf(m5, __shfl_xor(m5, 32));
      m6 = fmaxf(m6, __shfl_xor(m6, 8));  m6 = fmaxf(m6, __shfl_xor(m6, 16));  m6 = fmaxf(m6, __shfl_xor(m6, 32));
      m7 = fmaxf(m7, __shfl_xor(m7, 8));  m7 = fmaxf(m7, __shfl_xor(m7, 16));  m7 = fmaxf(m7, __shfl_xor(m7, 32));
      if (ch == 0) {
        // pixels p8+0..p8+7 -> cols 2+p8 .. 9+p8 (8B-aligned v2f stores)
        *(v2f*)&vbuf[cur ^ 1][lr][2 + p8] = (v2f){m0, m1};
        *(v2f*)&vbuf[cur ^ 1][lr][4 + p8] = (v2f){m2, m3};
        *(v2f*)&vbuf[cur ^ 1][lr][6 + p8] = (v2f){m4, m5};
        *(v2f*)&vbuf[cur ^ 1][lr][8 + p8] = (v2f){m6, m7};
      }
    }
    __syncthreads();
    cur ^= 1;
  }

  // final step t=10 + projection: wave owns row a0+wave
  {
    int r = a0 + wave;
    int lr = r - a0 + 22;
    const float* qrow = &q0b[((size_t)r * 8 + ch) * 64 + p8];
    float4 qa = *(const float4*)qrow;
    float4 qb = *(const float4*)(qrow + 4);
    v2f acc[4];
#pragma unroll
    for (int j = 0; j < 4; ++j) acc[j] = (v2f){0.f, 0.f};
#pragma unroll
    for (int jj = 0; jj < 5; ++jj) {
      const float* row = &vbuf[cur][lr - 2 + jj][p8];
      float4 fa = *(const float4*)row;
      float4 fb = *(const float4*)(row + 4);
      float4 fc = *(const float4*)(row + 8);
      float f[12] = {fa.x, fa.y, fa.z, fa.w, fb.x, fb.y,
                     fb.z, fb.w, fc.x, fc.y, fc.z, fc.w};
#pragma unroll
      for (int kx = 0; kx < 5; ++kx) {
        float wk = wr[jj * 5 + kx];
        v2f wk2 = (v2f){wk, wk};
#pragma unroll
        for (int j = 0; j < 4; ++j)
          acc[j] += wk2 * (v2f){f[2 * j + kx], f[2 * j + 1 + kx]};
      }
    }
    acc[0] += (v2f){qa.x, qa.y};
    acc[1] += (v2f){qa.z, qa.w};
    acc[2] += (v2f){qb.x, qb.y};
    acc[3] += (v2f){qb.z, qb.w};
    // projection: partial from this lane's channel, butterfly-sum over ch
    float fcp[4];
#pragma unroll
    for (int a = 0; a < 4; ++a) fcp[a] = fc_w[a * 8 + ch];
    float qv[8] = {acc[0].x, acc[0].y, acc[1].x, acc[1].y,
                   acc[2].x, acc[2].y, acc[3].x, acc[3].y};
#pragma unroll
    for (int i = 0; i < 8; ++i) {
      float p0 = fcp[0] * qv[i];
      float p1 = fcp[1] * qv[i];
      float p2 = fcp[2] * qv[i];
      float p3 = fcp[3] * qv[i];
      p0 += __shfl_xor(p0, 8); p0 += __shfl_xor(p0, 16); p0 += __shfl_xor(p0, 32);
      p1 += __shfl_xor(p1, 8); p1 += __shfl_xor(p1, 16); p1 += __shfl_xor(p1, 32);
      p2 += __shfl_xor(p2, 8); p2 += __shfl_xor(p2, 16); p2 += __shfl_xor(p2, 32);
      p3 += __shfl_xor(p3, 8); p3 += __shfl_xor(p3, 16); p3 += __shfl_xor(p3, 32);
      if (ch == 0)
        *(float4*)&out[((size_t)((b * 64 + r) * 64 + p8 + i)) * 4] =
            make_float4(p0, p1, p2, p3);
    }
  }
}

extern "C" void kernel_launch(void* const* d_in, const int* in_sizes, int n_in,
                              void* d_out, int out_size, void* d_ws, size_t ws_size,
                              hipStream_t stream) {
  const int* maze = (const int*)d_in[0];
  const float* emb = (const float*)d_in[1];
  const float* encode_w = (const float*)d_in[2];
  const float* encode_b = (const float*)d_in[3];
  const float* r_w = (const float*)d_in[4];
  const float* q_w = (const float*)d_in[5];
  const float* w = (const float*)d_in[6];
  const float* fc_w = (const float*)d_in[7];
  float* out = (float*)d_out;

  float* q0g = (float*)d_ws;  // 64*64*8*64 floats = 8 MB

  rq_kernel<<<dim3(4, 64), 512, 0, stream>>>(maze, emb, encode_w, encode_b,
                                             r_w, q_w, q0g);
  vi_kernel<<<dim3(4, 64), 1024, 0, stream>>>(q0g, w, fc_w, out);
}

// Round 6
// 115.888 us; speedup vs baseline: 1.2553x; 1.2553x over previous
//
#include <hip/hip_runtime.h>
#include <hip/hip_bf16.h>

// Nav_64939905516231 (VIN value iteration), MI355X gfx950.
// B=64,H=W=64,dim_h=150,n_hat=8,n_act=4,K=10. fp32 in/out, maze int32.
// Collapses: r = conv5x5(m,W_eff)+b_eff (150ch folded); q_t = q0 + conv5x5(v,w).
// R28 = R26 structure + __launch_bounds__(1024) with NO min-waves arg.
// R25/R26/R27 all pinned VGPR_Count=64 (an 8-waves/SIMD budget) and spilled
// 15-25MB to scratch: the (1024,4) hint is interpreted blocks/CU-style ->
// 64 waves -> clamped to 8/SIMD -> 64-reg cap. Dropping the hint lets the
// 1024-thread block itself force <=128 VGPRs (16 waves resident, 4/SIMD),
// which is the occupancy target. R27's 1-ch/lane tap pattern also blew up
// LDS bank conflicts 50x -> reverted to R26's clean 2-ch/lane pattern:
// lane = (cq = lane>>4 channel pair, p4 = (lane&15)*4). Wave = 1 row x 64 px
// x 8 ch, wave-uniform r. Taps 4-way broadcast across cq groups; 8-ch max via
// shfl_xor(16,32); cq==0 writes combined row. 1 barrier/step, dbuf vbuf.
// ~44us ws-poison fill + ~18us dispatch are harness-fixed.

#define NHAT 8
#define DIMH 150

typedef float v2f __attribute__((ext_vector_type(2)));

// ------- rq: prep (parallel) + r = table-conv(maze) + q0 -------
// q0 layout: q0g[(((b*64+gy)*4 + j)*64 + gx)*2] v2f = ch pair (2j,2j+1).
__global__ __launch_bounds__(512) void rq_kernel(
    const int* __restrict__ maze, const float* __restrict__ emb,
    const float* __restrict__ encode_w, const float* __restrict__ encode_b,
    const float* __restrict__ r_w, const float* __restrict__ q_w,
    float* __restrict__ q0g) {
  __shared__ float wpart[5][50];
  __shared__ float bpart[152];
  __shared__ float weff[2][25];
  __shared__ float Ts[4][25];
  __shared__ float bsh;
  __shared__ v2f qw2[25][4];
  __shared__ unsigned char mzt[24][68];
  __shared__ float rt[20][68];

  int tid = threadIdx.x;
  int b = blockIdx.y, A0 = blockIdx.x * 16;

  // P0: weight stage + W_eff partials + maze tile
  if (tid < 100) {
    int k = tid >> 2, j = tid & 3;
    qw2[k][j] = (v2f){q_w[(2 * j) * 25 + k], q_w[(2 * j + 1) * 25 + k]};
  }
  if (tid >= 256 && tid < 506) {
    int t2 = tid - 256;
    int chunk = t2 / 50, ik = t2 % 50;
    int i = ik / 25, k = ik % 25;
    int c0 = chunk * 30;
    float s = 0.f;
    for (int c = c0; c < c0 + 30; ++c)
      s += r_w[c] * encode_w[c * 50 + i * 25 + k];
    wpart[chunk][ik] = s;
  }
  if (tid >= 100 && tid < 250) {
    int c = tid - 100;
    bpart[c] = r_w[c] * encode_b[c];
  }
  for (int i = tid; i < 24 * 68; i += 512) {
    int mr = i / 68, mc = i % 68;
    int gy = A0 - 4 + mr, gx = mc - 2;
    unsigned char v = 3;
    if (gy >= 0 && gy < 64 && gx >= 0 && gx < 64)
      v = (unsigned char)maze[(b * 64 + gy) * 64 + gx];
    mzt[mr][mc] = v;
  }
  __syncthreads();
  // P1: reduce
  if (tid < 50) {
    float s = 0.f;
#pragma unroll
    for (int ch = 0; ch < 5; ++ch) s += wpart[ch][tid];
    weff[tid / 25][tid % 25] = s;
  }
  if (tid == 50) {
    float s = 0.f;
    for (int c = 0; c < 150; ++c) s += bpart[c];
    bsh = s;
  }
  __syncthreads();
  // P2: T table
  if (tid < 100) {
    int val = tid / 25, k = tid % 25;
    float t = 0.f;
    if (val < 3) t = weff[0][k] * emb[val * 2] + weff[1][k] * emb[val * 2 + 1];
    Ts[val][k] = t;  // row 3 == 0 (padding sentinel)
  }
  __syncthreads();
  // P3: r tile rows [A0-2, A0+18)
  for (int i = tid; i < 20 * 68; i += 512) {
    int rr = i / 68, cc = i % 68;
    int gy = A0 - 2 + rr, gx = cc - 2;
    float v = 0.f;
    if (gy >= 0 && gy < 64 && gx >= 0 && gx < 64) {
      v = bsh;
#pragma unroll
      for (int ky = 0; ky < 5; ++ky)
#pragma unroll
        for (int kx = 0; kx < 5; ++kx)
          v += Ts[mzt[rr + ky][cc - 2 + kx]][ky * 5 + kx];
    }
    rt[rr][cc] = v;
  }
  __syncthreads();
  // P4: q0 on owned 16 rows -> [b][gy][chpair][gx] v2f
  for (int i = tid; i < 16 * 64; i += 512) {
    int ly = i >> 6, gx = i & 63;
    int gy = A0 + ly;
    v2f acc[4];
#pragma unroll
    for (int j = 0; j < 4; ++j) acc[j] = (v2f){0.f, 0.f};
#pragma unroll
    for (int ky = 0; ky < 5; ++ky)
#pragma unroll
      for (int kx = 0; kx < 5; ++kx) {
        int k = ky * 5 + kx;
        float vv = rt[ly + ky][gx + kx];
        v2f vv2 = (v2f){vv, vv};
#pragma unroll
        for (int j = 0; j < 4; ++j) acc[j] += qw2[k][j] * vv2;
      }
#pragma unroll
    for (int j = 0; j < 4; ++j)
      *(v2f*)&q0g[(((size_t)(b * 64 + gy) * 4 + j) * 64 + gx) * 2] = acc[j];
  }
}

// =============== vi: 10 fused VI steps + projection =================
// Block (1024 thr = 16 waves) owns rows [a0, a0+16); grid 256 (1 blk/CU).
// Lane: cq = lane>>4 (channel pair), p4 = (lane&15)*4 (4-px group).
// Wave = 1 row x 64 px x 8 ch, r = s + wave (+16 stride), wave-uniform.
// All 4 cq groups read the SAME vbuf taps (broadcast). 8-ch max via
// shfl_xor(16)+shfl_xor(32); cq==0 writes cols 2+p4..5+p4. 1 barrier/step.
__global__ __launch_bounds__(1024) void vi_kernel(
    const float* __restrict__ q0g, const float* __restrict__ w,
    const float* __restrict__ fc_w, float* __restrict__ out) {
  __shared__ __align__(16) float vbuf[2][60][68];  // 32.6 KB
  __shared__ v2f wl2[25][4];

  int tid = threadIdx.x;
  int b = blockIdx.y, a0 = blockIdx.x * 16;
  int wave = tid >> 6, lane = tid & 63;
  int cq = lane >> 4;        // channel pair 0..3
  int p4 = (lane & 15) * 4;  // px group start

  if (tid < 100) {
    int k = tid >> 2, j = tid & 3;
    wl2[k][j] = (v2f){w[(2 * j) * 25 + k], w[(2 * j + 1) * 25 + k]};
  }
  for (int i = tid; i < 2 * 60 * 68; i += 1024) ((float*)vbuf)[i] = 0.f;
  __syncthreads();

  // this lane's 2 channels -> 25 v2f = 50 regs
  v2f wr[25];
#pragma unroll
  for (int k = 0; k < 25; ++k) wr[k] = wl2[k][cq];

  const float* q0b = q0g + (size_t)b * 64 * 4 * 64 * 2;
  int cur = 0;

  // v0 = max_c q0 on [a0-20, a0+36): full 8ch per lane, waves stride 16 rows
  {
    int s = max(0, a0 - 20), e = min(64, a0 + 36);
    int gx = lane;
    for (int r = s + wave; r < e; r += 16) {
      v2f a0v = *(const v2f*)&q0b[(((size_t)r * 4 + 0) * 64 + gx) * 2];
      v2f a1v = *(const v2f*)&q0b[(((size_t)r * 4 + 1) * 64 + gx) * 2];
      v2f a2v = *(const v2f*)&q0b[(((size_t)r * 4 + 2) * 64 + gx) * 2];
      v2f a3v = *(const v2f*)&q0b[(((size_t)r * 4 + 3) * 64 + gx) * 2];
      float m = fmaxf(fmaxf(fmaxf(a0v.x, a0v.y), fmaxf(a1v.x, a1v.y)),
                      fmaxf(fmaxf(a2v.x, a2v.y), fmaxf(a3v.x, a3v.y)));
      vbuf[0][r - a0 + 22][gx + 2] = m;
    }
  }
  __syncthreads();

  for (int t = 1; t <= 9; ++t) {
    int hh = 2 * (10 - t);
    int s = max(0, a0 - hh), e = min(64, a0 + 16 + hh);
    for (int r = s + wave; r < e; r += 16) {  // wave-uniform row
      int lr = r - a0 + 22;
      const float4* qp =
          (const float4*)&q0b[(((size_t)r * 4 + cq) * 64 + p4) * 2];
      float4 qv0 = qp[0], qv1 = qp[1];
      v2f aA[4];
#pragma unroll
      for (int j = 0; j < 4; ++j) aA[j] = (v2f){0.f, 0.f};
#pragma unroll
      for (int jj = 0; jj < 5; ++jj) {
        const float* row = &vbuf[cur][lr - 2 + jj][p4];
        float4 fa = *(const float4*)row;
        float4 fb = *(const float4*)(row + 4);
        float f[8] = {fa.x, fa.y, fa.z, fa.w, fb.x, fb.y, fb.z, fb.w};
#pragma unroll
        for (int kx = 0; kx < 5; ++kx) {
          v2f wk = wr[jj * 5 + kx];
#pragma unroll
          for (int j = 0; j < 4; ++j) {
            v2f vv2 = (v2f){f[j + kx], f[j + kx]};
            aA[j] += wk * vv2;
          }
        }
      }
      // q0 added after the tap chain: L2 latency hides under FMAs
      aA[0] += (v2f){qv0.x, qv0.y};
      aA[1] += (v2f){qv0.z, qv0.w};
      aA[2] += (v2f){qv1.x, qv1.y};
      aA[3] += (v2f){qv1.z, qv1.w};
      float m0 = fmaxf(aA[0].x, aA[0].y), m1 = fmaxf(aA[1].x, aA[1].y);
      float m2 = fmaxf(aA[2].x, aA[2].y), m3 = fmaxf(aA[3].x, aA[3].y);
      // combine the 4 channel pairs in-register (butterfly over cq)
      m0 = fmaxf(m0, __shfl_xor(m0, 16)); m0 = fmaxf(m0, __shfl_xor(m0, 32));
      m1 = fmaxf(m1, __shfl_xor(m1, 16)); m1 = fmaxf(m1, __shfl_xor(m1, 32));
      m2 = fmaxf(m2, __shfl_xor(m2, 16)); m2 = fmaxf(m2, __shfl_xor(m2, 32));
      m3 = fmaxf(m3, __shfl_xor(m3, 16)); m3 = fmaxf(m3, __shfl_xor(m3, 32));
      if (cq == 0) {
        // pixels p4+0..p4+3 -> cols 2+p4 .. 5+p4 (8B-aligned v2f stores)
        *(v2f*)&vbuf[cur ^ 1][lr][2 + p4] = (v2f){m0, m1};
        *(v2f*)&vbuf[cur ^ 1][lr][4 + p4] = (v2f){m2, m3};
      }
    }
    __syncthreads();
    cur ^= 1;
  }

  // final step t=10 + projection: wave owns row a0+wave
  {
    int r = a0 + wave;
    int lr = r - a0 + 22;
    const float4* qp =
        (const float4*)&q0b[(((size_t)r * 4 + cq) * 64 + p4) * 2];
    float4 qv0 = qp[0], qv1 = qp[1];
    v2f aA[4];
#pragma unroll
    for (int j = 0; j < 4; ++j) aA[j] = (v2f){0.f, 0.f};
#pragma unroll
    for (int jj = 0; jj < 5; ++jj) {
      const float* row = &vbuf[cur][lr - 2 + jj][p4];
      float4 fa = *(const float4*)row;
      float4 fb = *(const float4*)(row + 4);
      float f[8] = {fa.x, fa.y, fa.z, fa.w, fb.x, fb.y, fb.z, fb.w};
#pragma unroll
      for (int kx = 0; kx < 5; ++kx) {
        v2f wk = wr[jj * 5 + kx];
#pragma unroll
        for (int j = 0; j < 4; ++j) {
          v2f vv2 = (v2f){f[j + kx], f[j + kx]};
          aA[j] += wk * vv2;
        }
      }
    }
    aA[0] += (v2f){qv0.x, qv0.y};
    aA[1] += (v2f){qv0.z, qv0.w};
    aA[2] += (v2f){qv1.x, qv1.y};
    aA[3] += (v2f){qv1.z, qv1.w};
    // partial projection from this lane's 2 channels, butterfly-sum over cq
    v2f fcp2[4];
#pragma unroll
    for (int a = 0; a < 4; ++a)
      fcp2[a] = (v2f){fc_w[a * 8 + 2 * cq], fc_w[a * 8 + 2 * cq + 1]};
#pragma unroll
    for (int j = 0; j < 4; ++j) {
      float p0 = fcp2[0].x * aA[j].x + fcp2[0].y * aA[j].y;
      float p1 = fcp2[1].x * aA[j].x + fcp2[1].y * aA[j].y;
      float p2 = fcp2[2].x * aA[j].x + fcp2[2].y * aA[j].y;
      float p3 = fcp2[3].x * aA[j].x + fcp2[3].y * aA[j].y;
      p0 += __shfl_xor(p0, 16); p0 += __shfl_xor(p0, 32);
      p1 += __shfl_xor(p1, 16); p1 += __shfl_xor(p1, 32);
      p2 += __shfl_xor(p2, 16); p2 += __shfl_xor(p2, 32);
      p3 += __shfl_xor(p3, 16); p3 += __shfl_xor(p3, 32);
      if (cq == 0)
        *(float4*)&out[((size_t)((b * 64 + r) * 64 + p4 + j)) * 4] =
            make_float4(p0, p1, p2, p3);
    }
  }
}

extern "C" void kernel_launch(void* const* d_in, const int* in_sizes, int n_in,
                              void* d_out, int out_size, void* d_ws, size_t ws_size,
                              hipStream_t stream) {
  const int* maze = (const int*)d_in[0];
  const float* emb = (const float*)d_in[1];
  const float* encode_w = (const float*)d_in[2];
  const float* encode_b = (const float*)d_in[3];
  const float* r_w = (const float*)d_in[4];
  const float* q_w = (const float*)d_in[5];
  const float* w = (const float*)d_in[6];
  const float* fc_w = (const float*)d_in[7];
  float* out = (float*)d_out;

  float* q0g = (float*)d_ws;  // 64*64*4*64*2 floats = 8 MB

  rq_kernel<<<dim3(4, 64), 512, 0, stream>>>(maze, emb, encode_w, encode_b,
                                             r_w, q_w, q0g);
  vi_kernel<<<dim3(4, 64), 1024, 0, stream>>>(q0g, w, fc_w, out);
}

// Round 7
// 113.948 us; speedup vs baseline: 1.2767x; 1.0170x over previous
//
#include <hip/hip_runtime.h>
#include <hip/hip_bf16.h>

// Nav_64939905516231 (VIN value iteration), MI355X gfx950.
// B=64,H=W=64,dim_h=150,n_hat=8,n_act=4,K=10. fp32 in/out, maze int32.
// Collapses: r = conv5x5(m,W_eff)+b_eff (150ch folded); q_t = q0 + conv5x5(v,w).
// R29 = R26/R28 structure at 768 threads (12 waves, 3 waves/SIMD).
// Evidence R25-R28: ANY 1024-thr block pins arch VGPRs at 64 (hint-independent;
// R26 vs R28 counters bit-identical) and the ~95-reg live set spills ~15MB to
// scratch. At 12 waves/CU the budget is 512/3 ~= 170 regs/wave -> the R26 live
// set fits with headroom, zero structural change. 3/SIMD = +50% latency hiding
// over R23's 2/SIMD (best measured, vi ~43us).
// Lane map: cq = lane>>4 (channel pair), p4 = (lane&15)*4. Wave = 1 row x
// 64 px x 8 ch, wave-uniform r, rows stride 12. Taps 4-way broadcast across
// cq groups; 8-ch max via shfl_xor(16,32); cq==0 writes combined row.
// 1 barrier/step, dbuf vbuf. ~44us ws fill + ~18us dispatch harness-fixed.

#define NHAT 8
#define DIMH 150
#define VI_WAVES 12

typedef float v2f __attribute__((ext_vector_type(2)));

// ------- rq: prep (parallel) + r = table-conv(maze) + q0 -------
// q0 layout: q0g[(((b*64+gy)*4 + j)*64 + gx)*2] v2f = ch pair (2j,2j+1).
__global__ __launch_bounds__(512) void rq_kernel(
    const int* __restrict__ maze, const float* __restrict__ emb,
    const float* __restrict__ encode_w, const float* __restrict__ encode_b,
    const float* __restrict__ r_w, const float* __restrict__ q_w,
    float* __restrict__ q0g) {
  __shared__ float wpart[5][50];
  __shared__ float bpart[152];
  __shared__ float weff[2][25];
  __shared__ float Ts[4][25];
  __shared__ float bsh;
  __shared__ v2f qw2[25][4];
  __shared__ unsigned char mzt[24][68];
  __shared__ float rt[20][68];

  int tid = threadIdx.x;
  int b = blockIdx.y, A0 = blockIdx.x * 16;

  // P0: weight stage + W_eff partials + maze tile
  if (tid < 100) {
    int k = tid >> 2, j = tid & 3;
    qw2[k][j] = (v2f){q_w[(2 * j) * 25 + k], q_w[(2 * j + 1) * 25 + k]};
  }
  if (tid >= 256 && tid < 506) {
    int t2 = tid - 256;
    int chunk = t2 / 50, ik = t2 % 50;
    int i = ik / 25, k = ik % 25;
    int c0 = chunk * 30;
    float s = 0.f;
    for (int c = c0; c < c0 + 30; ++c)
      s += r_w[c] * encode_w[c * 50 + i * 25 + k];
    wpart[chunk][ik] = s;
  }
  if (tid >= 100 && tid < 250) {
    int c = tid - 100;
    bpart[c] = r_w[c] * encode_b[c];
  }
  for (int i = tid; i < 24 * 68; i += 512) {
    int mr = i / 68, mc = i % 68;
    int gy = A0 - 4 + mr, gx = mc - 2;
    unsigned char v = 3;
    if (gy >= 0 && gy < 64 && gx >= 0 && gx < 64)
      v = (unsigned char)maze[(b * 64 + gy) * 64 + gx];
    mzt[mr][mc] = v;
  }
  __syncthreads();
  // P1: reduce
  if (tid < 50) {
    float s = 0.f;
#pragma unroll
    for (int ch = 0; ch < 5; ++ch) s += wpart[ch][tid];
    weff[tid / 25][tid % 25] = s;
  }
  if (tid == 50) {
    float s = 0.f;
    for (int c = 0; c < 150; ++c) s += bpart[c];
    bsh = s;
  }
  __syncthreads();
  // P2: T table
  if (tid < 100) {
    int val = tid / 25, k = tid % 25;
    float t = 0.f;
    if (val < 3) t = weff[0][k] * emb[val * 2] + weff[1][k] * emb[val * 2 + 1];
    Ts[val][k] = t;  // row 3 == 0 (padding sentinel)
  }
  __syncthreads();
  // P3: r tile rows [A0-2, A0+18)
  for (int i = tid; i < 20 * 68; i += 512) {
    int rr = i / 68, cc = i % 68;
    int gy = A0 - 2 + rr, gx = cc - 2;
    float v = 0.f;
    if (gy >= 0 && gy < 64 && gx >= 0 && gx < 64) {
      v = bsh;
#pragma unroll
      for (int ky = 0; ky < 5; ++ky)
#pragma unroll
        for (int kx = 0; kx < 5; ++kx)
          v += Ts[mzt[rr + ky][cc - 2 + kx]][ky * 5 + kx];
    }
    rt[rr][cc] = v;
  }
  __syncthreads();
  // P4: q0 on owned 16 rows -> [b][gy][chpair][gx] v2f
  for (int i = tid; i < 16 * 64; i += 512) {
    int ly = i >> 6, gx = i & 63;
    int gy = A0 + ly;
    v2f acc[4];
#pragma unroll
    for (int j = 0; j < 4; ++j) acc[j] = (v2f){0.f, 0.f};
#pragma unroll
    for (int ky = 0; ky < 5; ++ky)
#pragma unroll
      for (int kx = 0; kx < 5; ++kx) {
        int k = ky * 5 + kx;
        float vv = rt[ly + ky][gx + kx];
        v2f vv2 = (v2f){vv, vv};
#pragma unroll
        for (int j = 0; j < 4; ++j) acc[j] += qw2[k][j] * vv2;
      }
#pragma unroll
    for (int j = 0; j < 4; ++j)
      *(v2f*)&q0g[(((size_t)(b * 64 + gy) * 4 + j) * 64 + gx) * 2] = acc[j];
  }
}

// =============== vi: 10 fused VI steps + projection =================
// Block (768 thr = 12 waves, 3 waves/SIMD) owns rows [a0, a0+16); grid 256.
// Lane: cq = lane>>4 (channel pair), p4 = (lane&15)*4 (4-px group).
// Wave = 1 row x 64 px x 8 ch, r = s + wave (+12 stride), wave-uniform.
// All 4 cq groups read the SAME vbuf taps (broadcast). 8-ch max via
// shfl_xor(16)+shfl_xor(32); cq==0 writes cols 2+p4..5+p4. 1 barrier/step.
__global__ __launch_bounds__(768) void vi_kernel(
    const float* __restrict__ q0g, const float* __restrict__ w,
    const float* __restrict__ fc_w, float* __restrict__ out) {
  __shared__ __align__(16) float vbuf[2][60][68];  // 32.6 KB
  __shared__ v2f wl2[25][4];

  int tid = threadIdx.x;
  int b = blockIdx.y, a0 = blockIdx.x * 16;
  int wave = tid >> 6, lane = tid & 63;
  int cq = lane >> 4;        // channel pair 0..3
  int p4 = (lane & 15) * 4;  // px group start

  if (tid < 100) {
    int k = tid >> 2, j = tid & 3;
    wl2[k][j] = (v2f){w[(2 * j) * 25 + k], w[(2 * j + 1) * 25 + k]};
  }
  for (int i = tid; i < 2 * 60 * 68; i += 768) ((float*)vbuf)[i] = 0.f;
  __syncthreads();

  // this lane's 2 channels -> 25 v2f = 50 regs (fits the 3-wave/SIMD budget)
  v2f wr[25];
#pragma unroll
  for (int k = 0; k < 25; ++k) wr[k] = wl2[k][cq];

  const float* q0b = q0g + (size_t)b * 64 * 4 * 64 * 2;
  int cur = 0;

  // v0 = max_c q0 on [a0-20, a0+36): full 8ch per lane, waves stride 12 rows
  {
    int s = max(0, a0 - 20), e = min(64, a0 + 36);
    int gx = lane;
    for (int r = s + wave; r < e; r += VI_WAVES) {
      v2f a0v = *(const v2f*)&q0b[(((size_t)r * 4 + 0) * 64 + gx) * 2];
      v2f a1v = *(const v2f*)&q0b[(((size_t)r * 4 + 1) * 64 + gx) * 2];
      v2f a2v = *(const v2f*)&q0b[(((size_t)r * 4 + 2) * 64 + gx) * 2];
      v2f a3v = *(const v2f*)&q0b[(((size_t)r * 4 + 3) * 64 + gx) * 2];
      float m = fmaxf(fmaxf(fmaxf(a0v.x, a0v.y), fmaxf(a1v.x, a1v.y)),
                      fmaxf(fmaxf(a2v.x, a2v.y), fmaxf(a3v.x, a3v.y)));
      vbuf[0][r - a0 + 22][gx + 2] = m;
    }
  }
  __syncthreads();

  for (int t = 1; t <= 9; ++t) {
    int hh = 2 * (10 - t);
    int s = max(0, a0 - hh), e = min(64, a0 + 16 + hh);
    for (int r = s + wave; r < e; r += VI_WAVES) {  // wave-uniform row
      int lr = r - a0 + 22;
      const float4* qp =
          (const float4*)&q0b[(((size_t)r * 4 + cq) * 64 + p4) * 2];
      float4 qv0 = qp[0], qv1 = qp[1];
      v2f aA[4];
#pragma unroll
      for (int j = 0; j < 4; ++j) aA[j] = (v2f){0.f, 0.f};
#pragma unroll
      for (int jj = 0; jj < 5; ++jj) {
        const float* row = &vbuf[cur][lr - 2 + jj][p4];
        float4 fa = *(const float4*)row;
        float4 fb = *(const float4*)(row + 4);
        float f[8] = {fa.x, fa.y, fa.z, fa.w, fb.x, fb.y, fb.z, fb.w};
#pragma unroll
        for (int kx = 0; kx < 5; ++kx) {
          v2f wk = wr[jj * 5 + kx];
#pragma unroll
          for (int j = 0; j < 4; ++j) {
            v2f vv2 = (v2f){f[j + kx], f[j + kx]};
            aA[j] += wk * vv2;
          }
        }
      }
      // q0 added after the tap chain: L2 latency hides under FMAs
      aA[0] += (v2f){qv0.x, qv0.y};
      aA[1] += (v2f){qv0.z, qv0.w};
      aA[2] += (v2f){qv1.x, qv1.y};
      aA[3] += (v2f){qv1.z, qv1.w};
      float m0 = fmaxf(aA[0].x, aA[0].y), m1 = fmaxf(aA[1].x, aA[1].y);
      float m2 = fmaxf(aA[2].x, aA[2].y), m3 = fmaxf(aA[3].x, aA[3].y);
      // combine the 4 channel pairs in-register (butterfly over cq)
      m0 = fmaxf(m0, __shfl_xor(m0, 16)); m0 = fmaxf(m0, __shfl_xor(m0, 32));
      m1 = fmaxf(m1, __shfl_xor(m1, 16)); m1 = fmaxf(m1, __shfl_xor(m1, 32));
      m2 = fmaxf(m2, __shfl_xor(m2, 16)); m2 = fmaxf(m2, __shfl_xor(m2, 32));
      m3 = fmaxf(m3, __shfl_xor(m3, 16)); m3 = fmaxf(m3, __shfl_xor(m3, 32));
      if (cq == 0) {
        // pixels p4+0..p4+3 -> cols 2+p4 .. 5+p4 (8B-aligned v2f stores)
        *(v2f*)&vbuf[cur ^ 1][lr][2 + p4] = (v2f){m0, m1};
        *(v2f*)&vbuf[cur ^ 1][lr][4 + p4] = (v2f){m2, m3};
      }
    }
    __syncthreads();
    cur ^= 1;
  }

  // final step t=10 + projection: 12 waves cover rows [a0, a0+16) in 2 trips
  for (int r = a0 + wave; r < a0 + 16; r += VI_WAVES) {
    int lr = r - a0 + 22;
    const float4* qp =
        (const float4*)&q0b[(((size_t)r * 4 + cq) * 64 + p4) * 2];
    float4 qv0 = qp[0], qv1 = qp[1];
    v2f aA[4];
#pragma unroll
    for (int j = 0; j < 4; ++j) aA[j] = (v2f){0.f, 0.f};
#pragma unroll
    for (int jj = 0; jj < 5; ++jj) {
      const float* row = &vbuf[cur][lr - 2 + jj][p4];
      float4 fa = *(const float4*)row;
      float4 fb = *(const float4*)(row + 4);
      float f[8] = {fa.x, fa.y, fa.z, fa.w, fb.x, fb.y, fb.z, fb.w};
#pragma unroll
      for (int kx = 0; kx < 5; ++kx) {
        v2f wk = wr[jj * 5 + kx];
#pragma unroll
        for (int j = 0; j < 4; ++j) {
          v2f vv2 = (v2f){f[j + kx], f[j + kx]};
          aA[j] += wk * vv2;
        }
      }
    }
    aA[0] += (v2f){qv0.x, qv0.y};
    aA[1] += (v2f){qv0.z, qv0.w};
    aA[2] += (v2f){qv1.x, qv1.y};
    aA[3] += (v2f){qv1.z, qv1.w};
    // partial projection from this lane's 2 channels, butterfly-sum over cq
    v2f fcp2[4];
#pragma unroll
    for (int a = 0; a < 4; ++a)
      fcp2[a] = (v2f){fc_w[a * 8 + 2 * cq], fc_w[a * 8 + 2 * cq + 1]};
#pragma unroll
    for (int j = 0; j < 4; ++j) {
      float p0 = fcp2[0].x * aA[j].x + fcp2[0].y * aA[j].y;
      float p1 = fcp2[1].x * aA[j].x + fcp2[1].y * aA[j].y;
      float p2 = fcp2[2].x * aA[j].x + fcp2[2].y * aA[j].y;
      float p3 = fcp2[3].x * aA[j].x + fcp2[3].y * aA[j].y;
      p0 += __shfl_xor(p0, 16); p0 += __shfl_xor(p0, 32);
      p1 += __shfl_xor(p1, 16); p1 += __shfl_xor(p1, 32);
      p2 += __shfl_xor(p2, 16); p2 += __shfl_xor(p2, 32);
      p3 += __shfl_xor(p3, 16); p3 += __shfl_xor(p3, 32);
      if (cq == 0)
        *(float4*)&out[((size_t)((b * 64 + r) * 64 + p4 + j)) * 4] =
            make_float4(p0, p1, p2, p3);
    }
  }
}

extern "C" void kernel_launch(void* const* d_in, const int* in_sizes, int n_in,
                              void* d_out, int out_size, void* d_ws, size_t ws_size,
                              hipStream_t stream) {
  const int* maze = (const int*)d_in[0];
  const float* emb = (const float*)d_in[1];
  const float* encode_w = (const float*)d_in[2];
  const float* encode_b = (const float*)d_in[3];
  const float* r_w = (const float*)d_in[4];
  const float* q_w = (const float*)d_in[5];
  const float* w = (const float*)d_in[6];
  const float* fc_w = (const float*)d_in[7];
  float* out = (float*)d_out;

  float* q0g = (float*)d_ws;  // 64*64*4*64*2 floats = 8 MB

  rq_kernel<<<dim3(4, 64), 512, 0, stream>>>(maze, emb, encode_w, encode_b,
                                             r_w, q_w, q0g);
  vi_kernel<<<dim3(4, 64), 768, 0, stream>>>(q0g, w, fc_w, out);
}